// Round 14
// baseline (188.688 us; speedup 1.0000x reference)
//
#include <hip/hip_runtime.h>
#include <hip/hip_bf16.h>

#define N 8192
#define D_IN 512
#define D_OUT 64
#define ALPHA 0.2f
#define BM 32
#define NRB (N / BM)            // 256 row-blocks
#define NSPLIT 4
#define KSEG (N / NSPLIT)       // 2048 cols per split
#define NSH (KSEG / 128)        // 16 steps; wave covers 32 of each 128 cols/step

typedef __attribute__((ext_vector_type(4))) float f32x4;
typedef __attribute__((ext_vector_type(8))) short bf16x8;

static __device__ __forceinline__ unsigned pk_bf16(float lo, float hi) {
    unsigned ulo = __bfloat16_as_ushort(__float2bfloat16(lo));
    unsigned uhi = __bfloat16_as_ushort(__float2bfloat16(hi));
    return (uhi << 16) | ulo;
}

// Kernel 0: adj -> 1 bit/elem mask. Deep-pipelined: all 16 float4 loads issued
// BEFORE any dependent convert (16 KB in flight per wave), then convert+store.
// msk byte (f>>3) bit z = adj[f+z] > 0 — identical layout to R9-R13.
__global__ __launch_bounds__(256) void gat_mask_kernel(
    const float* __restrict__ adj, unsigned char* __restrict__ msk)
{
    size_t wave = ((size_t)blockIdx.x * 256 + threadIdx.x) >> 6;
    int lane = threadIdx.x & 63;
    const float* base = adj + wave * 4096 + (size_t)lane * 8;
    float4 v[16];
#pragma unroll
    for (int it = 0; it < 8; ++it) {
        v[2 * it]     = *(const float4*)(base + it * 512);
        v[2 * it + 1] = *(const float4*)(base + it * 512 + 4);
    }
    size_t bo = wave * 512 + lane;
#pragma unroll
    for (int it = 0; it < 8; ++it) {
        float4 v0 = v[2 * it], v1 = v[2 * it + 1];
        unsigned b =  (unsigned)(v0.x > 0.f)
                   | ((unsigned)(v0.y > 0.f) << 1)
                   | ((unsigned)(v0.z > 0.f) << 2)
                   | ((unsigned)(v0.w > 0.f) << 3)
                   | ((unsigned)(v1.x > 0.f) << 4)
                   | ((unsigned)(v1.y > 0.f) << 5)
                   | ((unsigned)(v1.z > 0.f) << 6)
                   | ((unsigned)(v1.w > 0.f) << 7);
        msk[bo + it * 64] = (unsigned char)b;
    }
}

// Kernel 1: h = input @ W -> pre-swizzled MFMA B-frags (hpk) + s1/s2 (verified R11+).
__global__ __launch_bounds__(256) void gat_h_kernel(
    const float* __restrict__ input, const float* __restrict__ W,
    const float* __restrict__ a, unsigned short* __restrict__ hpk,
    float* __restrict__ s1, float* __restrict__ s2)
{
    __shared__ float hp[4][4][64];
    int ws   = threadIdx.x >> 6;
    int lane = threadIdx.x & 63;
    int row0 = blockIdx.x * 4;
    const float* in0 = input + (size_t)row0 * D_IN + ws * 128;
    const float* Wp  = W + ws * 128 * D_OUT;
    float acc[4] = {0.f, 0.f, 0.f, 0.f};
#pragma unroll 4
    for (int k = 0; k < 128; ++k) {
        float wk = Wp[k * D_OUT + lane];
#pragma unroll
        for (int r = 0; r < 4; ++r)
            acc[r] = fmaf(in0[r * D_IN + k], wk, acc[r]);
    }
#pragma unroll
    for (int r = 0; r < 4; ++r) hp[ws][r][lane] = acc[r];
    __syncthreads();
    if (ws == 0) {
        float h[4];
#pragma unroll
        for (int r = 0; r < 4; ++r)
            h[r] = (hp[0][r][lane] + hp[1][r][lane]) + (hp[2][r][lane] + hp[3][r][lane]);
        int kw = row0 >> 5, kb = (row0 >> 3) & 3, e0 = row0 & 7;
        int dw = lane >> 4, dd = lane & 15;
        size_t off = ((size_t)((kw * 4 + dw) * 64) + kb * 16 + dd) * 8 + e0;
        uint2 hv;
        hv.x = pk_bf16(h[0], h[1]);
        hv.y = pk_bf16(h[2], h[3]);
        *(uint2*)(hpk + off) = hv;
        float a1 = a[lane], a2 = a[D_OUT + lane];
#pragma unroll
        for (int r = 0; r < 4; ++r) {
            float p1 = h[r] * a1;
            float p2 = h[r] * a2;
#pragma unroll
            for (int off2 = 32; off2; off2 >>= 1) {
                p1 += __shfl_xor(p1, off2, 64);
                p2 += __shfl_xor(p2, off2, 64);
            }
            if (lane == 0) { s1[row0 + r] = p1; s2[row0 + r] = p2; }
        }
    }
}

struct SSP { float4 sA, sB; };          // s2 pair for one 32-col slice
struct UBP { uint4 b0, b1, b2, b3; };   // 4 d-window B-frags for one 32-k window

// Kernel 2: masked-softmax @ h via MFMA — R9's verified barrier-free structure,
// BM=32 (2 row-groups share every hpk fragment load -> L2 traffic halved to
// 256 MB). Wave ws owns 32-col k-slices; lane (kb,i) computes w[8] natively as
// the MFMA A-frag for each row-group; 8 MFMA/step. Mask bytes from global msk
// (L2), 2-step register prefetch on msk/s2/hpk. LDS combine across 4 waves.
__global__ __launch_bounds__(256, 4) void gat_flash_kernel(
    const unsigned char* __restrict__ msk, const unsigned short* __restrict__ hpk,
    const float* __restrict__ s1, const float* __restrict__ s2,
    float* __restrict__ pacc, float* __restrict__ plsum)
{
    __shared__ float Cl[4][BM][D_OUT];   // 32 KB (end only)
    __shared__ float lsl[4][BM];

    const int tid  = threadIdx.x;
    const int lane = tid & 63;
    const int ws   = tid >> 6;
    const int i    = lane & 15;          // A-frag row within 16-group
    const int kb   = lane >> 4;          // k-subwindow
    const int hf   = blockIdx.x >> 8;    // k-split 0..3
    const int rb   = blockIdx.x & 255;   // row-block (32 rows)
    const int r0   = rb * BM;

    const unsigned char* mb = msk + ((size_t)(r0 + i) << 10) + hf * 256 + ws * 4 + kb;
    const float* s2b = s2 + hf * KSEG + ws * 32 + kb * 8;
    const unsigned short* hb = hpk + (((size_t)(hf * 64 + ws)) << 11) + (lane << 3);

    float s1r[2], eref[2];
#pragma unroll
    for (int ag = 0; ag < 2; ++ag) {
        int rg = r0 + ag * 16 + i;
        s1r[ag] = s1[rg];
        float e = s1r[ag] + s2[rg];              // diagonal logit (adj[i][i]=1)
        eref[ag] = e > 0.f ? e : ALPHA * e;      // leaky_relu
    }
    float lsum[2] = {0.f, 0.f};
    f32x4 acc[2][4];
#pragma unroll
    for (int ag = 0; ag < 2; ++ag)
#pragma unroll
        for (int dw = 0; dw < 4; ++dw) acc[ag][dw] = f32x4{0.f, 0.f, 0.f, 0.f};

    auto issue_s = [&](SSP& p, int ps) {
        p.sA = *(const float4*)(s2b + ps * 128);
        p.sB = *(const float4*)(s2b + ps * 128 + 4);
    };
    auto issue_u = [&](UBP& p, int ps) {
        const unsigned short* f = hb + ((size_t)ps << 13);
        p.b0 = *(const uint4*)(f);
        p.b1 = *(const uint4*)(f + 512);
        p.b2 = *(const uint4*)(f + 1024);
        p.b3 = *(const uint4*)(f + 1536);
    };
    auto issue_m = [&](unsigned& m0, unsigned& m1, int ps) {
        m0 = mb[ps * 16];
        m1 = mb[ps * 16 + 16384];                // row +16 (16 rows x 1024 B)
    };
    auto step = [&](const SSP& p, const UBP& u, unsigned m0, unsigned m1) {
        const float* sv0 = (const float*)&p.sA;
        const float* sv1 = (const float*)&p.sB;
        const uint4 ub[4] = {u.b0, u.b1, u.b2, u.b3};
        const unsigned mm[2] = {m0, m1};
#pragma unroll
        for (int ag = 0; ag < 2; ++ag) {
            float w[8];
#pragma unroll
            for (int z = 0; z < 4; ++z) {
                float e0 = s1r[ag] + sv0[z]; e0 = e0 > 0.f ? e0 : ALPHA * e0;
                float e1 = s1r[ag] + sv1[z]; e1 = e1 > 0.f ? e1 : ALPHA * e1;
                float w0 = __expf(e0 - eref[ag]);
                float w1 = __expf(e1 - eref[ag]);
                w[z]     = ((mm[ag] >> z) & 1u)       ? w0 : 0.f;
                w[z + 4] = ((mm[ag] >> (z + 4)) & 1u) ? w1 : 0.f;
            }
#pragma unroll
            for (int z = 0; z < 8; ++z) lsum[ag] += w[z];
            uint4 pk;
            pk.x = pk_bf16(w[0], w[1]); pk.y = pk_bf16(w[2], w[3]);
            pk.z = pk_bf16(w[4], w[5]); pk.w = pk_bf16(w[6], w[7]);
            bf16x8 A = __builtin_bit_cast(bf16x8, pk);
            acc[ag][0] = __builtin_amdgcn_mfma_f32_16x16x32_bf16(A, __builtin_bit_cast(bf16x8, ub[0]), acc[ag][0], 0, 0, 0);
            acc[ag][1] = __builtin_amdgcn_mfma_f32_16x16x32_bf16(A, __builtin_bit_cast(bf16x8, ub[1]), acc[ag][1], 0, 0, 0);
            acc[ag][2] = __builtin_amdgcn_mfma_f32_16x16x32_bf16(A, __builtin_bit_cast(bf16x8, ub[2]), acc[ag][2], 0, 0, 0);
            acc[ag][3] = __builtin_amdgcn_mfma_f32_16x16x32_bf16(A, __builtin_bit_cast(bf16x8, ub[3]), acc[ag][3], 0, 0, 0);
        }
    };

    SSP S0, S1; UBP U0, U1;
    unsigned m0a, m0b, m1a, m1b;
    issue_s(S0, 0); issue_u(U0, 0); issue_m(m0a, m0b, 0);
    issue_s(S1, 1); issue_u(U1, 1); issue_m(m1a, m1b, 1);
    for (int p = 0; p < NSH; p += 2) {
        step(S0, U0, m0a, m0b);
        if (p + 2 < NSH) { issue_s(S0, p + 2); issue_u(U0, p + 2); issue_m(m0a, m0b, p + 2); }
        step(S1, U1, m1a, m1b);
        if (p + 3 < NSH) { issue_s(S1, p + 3); issue_u(U1, p + 3); issue_m(m1a, m1b, p + 3); }
    }

    // lsum: lanes i, i+16, i+32, i+48 hold row-i k-slices of this wave
#pragma unroll
    for (int ag = 0; ag < 2; ++ag) {
        lsum[ag] += __shfl_xor(lsum[ag], 16, 64);
        lsum[ag] += __shfl_xor(lsum[ag], 32, 64);
    }
    if (lane < 16) {
        lsl[ws][lane]      = lsum[0];
        lsl[ws][16 + lane] = lsum[1];
    }
    // C k-partials: row = ag*16 + kb*4+reg, col = dw*16+i  (C/D frag layout)
#pragma unroll
    for (int ag = 0; ag < 2; ++ag)
#pragma unroll
        for (int dw = 0; dw < 4; ++dw)
#pragma unroll
            for (int reg = 0; reg < 4; ++reg)
                Cl[ws][ag * 16 + kb * 4 + reg][dw * 16 + i] = acc[ag][dw][reg];
    __syncthreads();

#pragma unroll
    for (int o = tid; o < BM * D_OUT; o += 256) {
        int row = o >> 6, d = o & 63;
        float v = (Cl[0][row][d] + Cl[1][row][d]) + (Cl[2][row][d] + Cl[3][row][d]);
        pacc[((size_t)hf * N + r0 + row) * 64 + d] = v;
    }
    if (tid < BM)
        plsum[hf * N + r0 + tid] =
            (lsl[0][tid] + lsl[1][tid]) + (lsl[2][tid] + lsl[3][tid]);
}

// Kernel 3: combine the 4 k-splits, normalize, elu.
__global__ __launch_bounds__(256) void gat_reduce_kernel(
    const float* __restrict__ pacc, const float* __restrict__ plsum,
    float* __restrict__ out)
{
    int idx = blockIdx.x * 256 + threadIdx.x;    // over N*64
    int row = idx >> 6;
    float aa = 0.f, l = 0.f;
#pragma unroll
    for (int hf = 0; hf < NSPLIT; ++hf) {
        aa += pacc[(size_t)hf * N * 64 + idx];
        l  += plsum[hf * N + row];
    }
    float o = aa / l;
    out[idx] = o > 0.f ? o : expm1f(o);          // elu
}

extern "C" void kernel_launch(void* const* d_in, const int* in_sizes, int n_in,
                              void* d_out, int out_size, void* d_ws, size_t ws_size,
                              hipStream_t stream) {
    const float* input = (const float*)d_in[0];   // (8192, 512) f32
    const float* adj   = (const float*)d_in[1];   // (8192, 8192) f32
    const float* W     = (const float*)d_in[2];   // (512, 64) f32
    const float* a     = (const float*)d_in[3];   // (128, 1) f32
    float* out = (float*)d_out;                   // (8192, 64) f32

    unsigned short* hpk = (unsigned short*)d_ws;          // 1 MB fragment buffer
    float* s1    = (float*)(hpk + (size_t)N * D_OUT);     // N f32
    float* s2    = s1 + N;                                // N f32
    float* pacc  = s2 + N;                                // NSPLIT*N*64 f32 = 8 MB
    float* plsum = pacc + (size_t)NSPLIT * N * 64;        // NSPLIT*N f32
    unsigned char* msk = (unsigned char*)(plsum + (size_t)NSPLIT * N);  // 8 MB

    gat_mask_kernel<<<4096, 256, 0, stream>>>(adj, msk);
    gat_h_kernel<<<2048, 256, 0, stream>>>(input, W, a, hpk, s1, s2);
    gat_flash_kernel<<<NRB * NSPLIT, 256, 0, stream>>>(msk, hpk, s1, s2, pacc, plsum);
    gat_reduce_kernel<<<N * 64 / 256, 256, 0, stream>>>(pacc, plsum, out);
}

// Round 15
// 138.958 us; speedup vs baseline: 1.3579x; 1.3579x over previous
//
#include <hip/hip_runtime.h>
#include <hip/hip_bf16.h>

#define N 8192
#define D_IN 512
#define D_OUT 64
#define ALPHA 0.2f
#define BM 16
#define NRB (N / BM)            // 512 row-blocks
#define NSPLIT 4
#define KSEG (N / NSPLIT)       // 2048 cols per split
#define NSH (KSEG / 128)        // 16 steps; wave covers 32 of each 128 cols/step

typedef __attribute__((ext_vector_type(4))) float f32x4;
typedef __attribute__((ext_vector_type(8))) short bf16x8;

static __device__ __forceinline__ unsigned pk_bf16(float lo, float hi) {
    unsigned ulo = __bfloat16_as_ushort(__float2bfloat16(lo));
    unsigned uhi = __bfloat16_as_ushort(__float2bfloat16(hi));
    return (uhi << 16) | ulo;
}

// Kernel 0: adj -> 1 bit/elem mask in FLASH-NATIVE transposed layout:
// uint index u = rb*4096 + hf*1024 + q*256 + ws*64 + kb*16 + i, byte j of u
// holds cols (hf*2048 + (q*4+j)*128 + ws*32 + kb*8 .. +8) of row rb*16+i.
// Reads stay row-major coalesced (16 float4 in flight/wave); stores scatter
// (posted, L2-merged). Flash then gathers with ONE coalesced uint/lane per 4 steps.
__global__ __launch_bounds__(256) void gat_mask_kernel(
    const float* __restrict__ adj, unsigned char* __restrict__ msk2)
{
    size_t wave = ((size_t)blockIdx.x * 256 + threadIdx.x) >> 6;
    int lane = threadIdx.x & 63;
    const float* base = adj + wave * 4096 + (size_t)lane * 8;
    float4 v[16];
#pragma unroll
    for (int it = 0; it < 8; ++it) {
        v[2 * it]     = *(const float4*)(base + it * 512);
        v[2 * it + 1] = *(const float4*)(base + it * 512 + 4);
    }
#pragma unroll
    for (int it = 0; it < 8; ++it) {
        float4 v0 = v[2 * it], v1 = v[2 * it + 1];
        unsigned b =  (unsigned)(v0.x > 0.f)
                   | ((unsigned)(v0.y > 0.f) << 1)
                   | ((unsigned)(v0.z > 0.f) << 2)
                   | ((unsigned)(v0.w > 0.f) << 3)
                   | ((unsigned)(v1.x > 0.f) << 4)
                   | ((unsigned)(v1.y > 0.f) << 5)
                   | ((unsigned)(v1.z > 0.f) << 6)
                   | ((unsigned)(v1.w > 0.f) << 7);
        size_t chunk = wave * 512 + (size_t)it * 64 + lane;   // 8-col chunk id
        int row = (int)(chunk >> 10);
        int cb  = (int)(chunk & 1023);
        int hf = cb >> 8, rem = cb & 255;
        int p = rem >> 4, ws = (rem >> 2) & 3, kb = rem & 3;
        int q = p >> 2, j = p & 3;
        unsigned u = ((unsigned)(row >> 4)) * 4096 + hf * 1024 + q * 256
                   + ws * 64 + kb * 16 + (row & 15);
        msk2[(size_t)u * 4 + j] = (unsigned char)b;
    }
}

// Kernel 1: h = input @ W -> pre-swizzled MFMA B-frags (hpk) + s1/s2 (verified R11+).
__global__ __launch_bounds__(256) void gat_h_kernel(
    const float* __restrict__ input, const float* __restrict__ W,
    const float* __restrict__ a, unsigned short* __restrict__ hpk,
    float* __restrict__ s1, float* __restrict__ s2)
{
    __shared__ float hp[4][4][64];
    int ws   = threadIdx.x >> 6;
    int lane = threadIdx.x & 63;
    int row0 = blockIdx.x * 4;
    const float* in0 = input + (size_t)row0 * D_IN + ws * 128;
    const float* Wp  = W + ws * 128 * D_OUT;
    float acc[4] = {0.f, 0.f, 0.f, 0.f};
#pragma unroll 4
    for (int k = 0; k < 128; ++k) {
        float wk = Wp[k * D_OUT + lane];
#pragma unroll
        for (int r = 0; r < 4; ++r)
            acc[r] = fmaf(in0[r * D_IN + k], wk, acc[r]);
    }
#pragma unroll
    for (int r = 0; r < 4; ++r) hp[ws][r][lane] = acc[r];
    __syncthreads();
    if (ws == 0) {
        float h[4];
#pragma unroll
        for (int r = 0; r < 4; ++r)
            h[r] = (hp[0][r][lane] + hp[1][r][lane]) + (hp[2][r][lane] + hp[3][r][lane]);
        int kw = row0 >> 5, kb = (row0 >> 3) & 3, e0 = row0 & 7;
        int dw = lane >> 4, dd = lane & 15;
        size_t off = ((size_t)((kw * 4 + dw) * 64) + kb * 16 + dd) * 8 + e0;
        uint2 hv;
        hv.x = pk_bf16(h[0], h[1]);
        hv.y = pk_bf16(h[2], h[3]);
        *(uint2*)(hpk + off) = hv;
        float a1 = a[lane], a2 = a[D_OUT + lane];
#pragma unroll
        for (int r = 0; r < 4; ++r) {
            float p1 = h[r] * a1;
            float p2 = h[r] * a2;
#pragma unroll
            for (int off2 = 32; off2; off2 >>= 1) {
                p1 += __shfl_xor(p1, off2, 64);
                p2 += __shfl_xor(p2, off2, 64);
            }
            if (lane == 0) { s1[row0 + r] = p1; s2[row0 + r] = p2; }
        }
    }
}

struct SSP { float4 sA, sB; };          // s2 pair for one 32-col slice
struct UBP { uint4 b0, b1, b2, b3; };   // 4 d-window B-frags for one 32-k window

// Kernel 2: masked-softmax @ h via MFMA — R9's verified barrier-free BM=16
// structure, unchanged except the mask path: ONE coalesced uint load per lane
// per 4 steps from the transposed msk2 (lane addr = base + lane*4), replacing
// 16-line scattered byte gathers. Split-K x4 partials out, LDS combine at end.
__global__ __launch_bounds__(256, 4) void gat_flash_kernel(
    const unsigned char* __restrict__ msk2, const unsigned short* __restrict__ hpk,
    const float* __restrict__ s1, const float* __restrict__ s2,
    float* __restrict__ pacc, float* __restrict__ plsum)
{
    __shared__ float Cl[4][BM][D_OUT];   // 16 KB (end only)
    __shared__ float lsl[4][BM];

    const int tid  = threadIdx.x;
    const int lane = tid & 63;
    const int ws   = tid >> 6;
    const int i    = lane & 15;          // A-frag row
    const int kb   = lane >> 4;          // k-subwindow
    const int hf   = blockIdx.x >> 9;    // k-split 0..3
    const int rb   = blockIdx.x & 511;   // row-block
    const int rg   = rb * BM + i;

    const unsigned* mb_u = (const unsigned*)msk2
        + (size_t)rb * 4096 + hf * 1024 + ws * 64 + lane;   // +q*256 per group
    const float* s2b = s2 + hf * KSEG + ws * 32 + kb * 8;
    const unsigned short* hb = hpk + (((size_t)(hf * 64 + ws)) << 11) + (lane << 3);

    float s1r  = s1[rg];
    float eref = s1r + s2[rg];                    // diagonal logit (adj[i][i]=1)
    eref = eref > 0.f ? eref : ALPHA * eref;      // leaky_relu
    float lsum = 0.f;
    f32x4 acc0 = {0,0,0,0}, acc1 = {0,0,0,0}, acc2 = {0,0,0,0}, acc3 = {0,0,0,0};

    auto issue_s = [&](SSP& p, int ps) {
        p.sA = *(const float4*)(s2b + ps * 128);
        p.sB = *(const float4*)(s2b + ps * 128 + 4);
    };
    auto issue_u = [&](UBP& p, int ps) {
        const unsigned short* f = hb + ((size_t)ps << 13);
        p.b0 = *(const uint4*)(f);
        p.b1 = *(const uint4*)(f + 512);
        p.b2 = *(const uint4*)(f + 1024);
        p.b3 = *(const uint4*)(f + 1536);
    };
    auto step = [&](const SSP& p, const UBP& u, unsigned m) {
        const float* sv0 = (const float*)&p.sA;
        const float* sv1 = (const float*)&p.sB;
        float w[8];
#pragma unroll
        for (int z = 0; z < 4; ++z) {
            float e0 = s1r + sv0[z]; e0 = e0 > 0.f ? e0 : ALPHA * e0;   // leaky_relu
            float e1 = s1r + sv1[z]; e1 = e1 > 0.f ? e1 : ALPHA * e1;
            float w0 = __expf(e0 - eref);
            float w1 = __expf(e1 - eref);
            w[z]     = ((m >> z) & 1u)       ? w0 : 0.f;
            w[z + 4] = ((m >> (z + 4)) & 1u) ? w1 : 0.f;
        }
#pragma unroll
        for (int z = 0; z < 8; ++z) lsum += w[z];
        uint4 pk;
        pk.x = pk_bf16(w[0], w[1]); pk.y = pk_bf16(w[2], w[3]);
        pk.z = pk_bf16(w[4], w[5]); pk.w = pk_bf16(w[6], w[7]);
        bf16x8 A = __builtin_bit_cast(bf16x8, pk);
        acc0 = __builtin_amdgcn_mfma_f32_16x16x32_bf16(A, __builtin_bit_cast(bf16x8, u.b0), acc0, 0, 0, 0);
        acc1 = __builtin_amdgcn_mfma_f32_16x16x32_bf16(A, __builtin_bit_cast(bf16x8, u.b1), acc1, 0, 0, 0);
        acc2 = __builtin_amdgcn_mfma_f32_16x16x32_bf16(A, __builtin_bit_cast(bf16x8, u.b2), acc2, 0, 0, 0);
        acc3 = __builtin_amdgcn_mfma_f32_16x16x32_bf16(A, __builtin_bit_cast(bf16x8, u.b3), acc3, 0, 0, 0);
    };

    SSP S0, S1; UBP U0, U1;
    issue_s(S0, 0); issue_u(U0, 0);
    issue_s(S1, 1); issue_u(U1, 1);
    unsigned mqc = mb_u[0];              // masks for steps 0..3 (byte j = step)
    unsigned mqn = mb_u[256];            // masks for steps 4..7
    for (int p = 0; p < NSH; p += 2) {
        if (p && (p & 3) == 0) {         // entering new 4-step group
            mqc = mqn;
            if (p < 12) mqn = mb_u[(size_t)(p / 4 + 1) * 256];
        }
        unsigned m0 = (mqc >> ((p & 3) * 8)) & 0xffu;
        unsigned m1 = (mqc >> ((p & 3) * 8 + 8)) & 0xffu;
        step(S0, U0, m0);
        if (p + 2 < NSH) { issue_s(S0, p + 2); issue_u(U0, p + 2); }
        step(S1, U1, m1);
        if (p + 3 < NSH) { issue_s(S1, p + 3); issue_u(U1, p + 3); }
    }

    // lsum: lanes i, i+16, i+32, i+48 hold row-i k-slices of this wave
    lsum += __shfl_xor(lsum, 16, 64);
    lsum += __shfl_xor(lsum, 32, 64);
    if (lane < 16) lsl[ws][lane] = lsum;

    // C k-partials: row = kb*4+reg, col = dw*16+i  (C/D frag layout)
    const f32x4 av[4] = {acc0, acc1, acc2, acc3};
#pragma unroll
    for (int dw = 0; dw < 4; ++dw)
#pragma unroll
        for (int reg = 0; reg < 4; ++reg)
            Cl[ws][kb * 4 + reg][dw * 16 + i] = av[dw][reg];
    __syncthreads();

#pragma unroll
    for (int o = tid; o < BM * D_OUT; o += 256) {
        int row = o >> 6, d = o & 63;
        float v = (Cl[0][row][d] + Cl[1][row][d]) + (Cl[2][row][d] + Cl[3][row][d]);
        pacc[((size_t)hf * N + rb * BM + row) * 64 + d] = v;
    }
    if (tid < BM)
        plsum[hf * N + rb * BM + tid] =
            (lsl[0][tid] + lsl[1][tid]) + (lsl[2][tid] + lsl[3][tid]);
}

// Kernel 3: combine the 4 k-splits, normalize, elu.
__global__ __launch_bounds__(256) void gat_reduce_kernel(
    const float* __restrict__ pacc, const float* __restrict__ plsum,
    float* __restrict__ out)
{
    int idx = blockIdx.x * 256 + threadIdx.x;    // over N*64
    int row = idx >> 6;
    float aa = 0.f, l = 0.f;
#pragma unroll
    for (int hf = 0; hf < NSPLIT; ++hf) {
        aa += pacc[(size_t)hf * N * 64 + idx];
        l  += plsum[hf * N + row];
    }
    float o = aa / l;
    out[idx] = o > 0.f ? o : expm1f(o);          // elu
}

extern "C" void kernel_launch(void* const* d_in, const int* in_sizes, int n_in,
                              void* d_out, int out_size, void* d_ws, size_t ws_size,
                              hipStream_t stream) {
    const float* input = (const float*)d_in[0];   // (8192, 512) f32
    const float* adj   = (const float*)d_in[1];   // (8192, 8192) f32
    const float* W     = (const float*)d_in[2];   // (512, 64) f32
    const float* a     = (const float*)d_in[3];   // (128, 1) f32
    float* out = (float*)d_out;                   // (8192, 64) f32

    unsigned short* hpk = (unsigned short*)d_ws;          // 1 MB fragment buffer
    float* s1    = (float*)(hpk + (size_t)N * D_OUT);     // N f32
    float* s2    = s1 + N;                                // N f32
    float* pacc  = s2 + N;                                // NSPLIT*N*64 f32 = 8 MB
    float* plsum = pacc + (size_t)NSPLIT * N * 64;        // NSPLIT*N f32
    unsigned char* msk2 = (unsigned char*)(plsum + (size_t)NSPLIT * N);  // 8 MB

    gat_mask_kernel<<<4096, 256, 0, stream>>>(adj, msk2);
    gat_h_kernel<<<2048, 256, 0, stream>>>(input, W, a, hpk, s1, s2);
    gat_flash_kernel<<<NRB * NSPLIT, 256, 0, stream>>>(msk2, hpk, s1, s2, pacc, plsum);
    gat_reduce_kernel<<<N * 64 / 256, 256, 0, stream>>>(pacc, plsum, out);
}